// Round 9
// baseline (289.504 us; speedup 1.0000x reference)
//
#include <hip/hip_runtime.h>
#include <hip/hip_bf16.h>
#include <stdint.h>

#define B_ 8
#define L_ 2048
#define V_ 8192
#define C_ 64
#define F_ 130   // 2*(C+1)

typedef float    f32x4  __attribute__((ext_vector_type(4)));
typedef float    f32x2  __attribute__((ext_vector_type(2)));
typedef short    s16x8  __attribute__((ext_vector_type(8)));
typedef __bf16   bf16x8 __attribute__((ext_vector_type(8)));
typedef uint32_t u32x4  __attribute__((ext_vector_type(4)));

#if __has_builtin(__builtin_amdgcn_exp2f)
#define EXP2(x) __builtin_amdgcn_exp2f(x)
#else
#define EXP2(x) exp2f(x)
#endif

#if __has_builtin(__builtin_elementwise_fma)
#define PK_FMA4(a,b,c) __builtin_elementwise_fma((a),(b),(c))
#else
__device__ __forceinline__ f32x4 PK_FMA4(f32x4 a, f32x4 b, f32x4 c) {
  f32x4 r; for (int i=0;i<4;++i) r[i]=fmaf(a[i],b[i],c[i]); return r;
}
#endif
#if __has_builtin(__builtin_elementwise_max)
#define PK_MAX4(a,b) __builtin_elementwise_max((a),(b))
#else
__device__ __forceinline__ f32x4 PK_MAX4(f32x4 a, f32x4 b) {
  f32x4 r; for (int i=0;i<4;++i) r[i]=fmaxf(a[i],b[i]); return r;
}
#endif

// K = 1/(2.5*ln2); w = exp(-d/2.5) = exp2(-K*d) = exp2(-sqrt(K^2*d2))
constexpr float KEXP2 = (float)(0.57707801635558535 * 0.57707801635558535);

__device__ __forceinline__ uint32_t pack2bf(float a, float b) {
  uint16_t ua = __builtin_bit_cast(uint16_t, (__bf16)a);
  uint16_t ub = __builtin_bit_cast(uint16_t, (__bf16)b);
  return (uint32_t)ua | ((uint32_t)ub << 16);
}

__device__ __forceinline__ float wave_sum(float v) {
  v += __shfl_xor(v, 1);  v += __shfl_xor(v, 2);  v += __shfl_xor(v, 4);
  v += __shfl_xor(v, 8);  v += __shfl_xor(v, 16); v += __shfl_xor(v, 32);
  return v;
}

// async global->LDS, 16B per lane: lds dest = wave-uniform base + lane*16
__device__ __forceinline__ void gload_lds16(const void* g, void* l) {
  __builtin_amdgcn_global_load_lds(
      (const __attribute__((address_space(1))) void*)g,
      (__attribute__((address_space(3))) void*)l, 16, 0, 0);
}

// ---------------------------------------------------------------------------
// PRE: unchanged from round 7/8 (passing, full coverage).
// blocks [0,1024): feats -> bf16 pre-swizzled 8KB k-tiles.
// blocks [1024,1536): verts -> vS2 pre-scaled {x',y',z',n2'} 1KB tiles.
// ---------------------------------------------------------------------------
__global__ __launch_bounds__(256) void pre_kernel(
    const float* __restrict__ verts_l, const float* __restrict__ verts_r,
    const float* __restrict__ feats_l, const float* __restrict__ feats_r,
    uint16_t* __restrict__ fT2, float* __restrict__ vS2)
{
  __shared__ float fs[64][68];
  const int blk = blockIdx.x, tid = threadIdx.x;
  if (blk < 1024) {
    const int p = blk >> 6, kt2 = blk & 63;      // 64-vert subtiles 2*kt2, 2*kt2+1
    const int side = p >> 3, bb = p & 7;
    const float* src = (side ? feats_r : feats_l) + (size_t)bb * (V_ * C_);
    #pragma unroll
    for (int sub = 0; sub < 2; ++sub) {
      const int ktile = kt2 * 2 + sub;
      const int v0 = ktile * 64;
      { // stage 64 rows x 64 ch, coalesced; column XOR-swizzle per 8-col block
        const int sv = tid >> 2, c0 = (tid & 3) * 16;
        const int m = ((sv >> 3) & 7) << 3;
        const float* s = src + (size_t)(v0 + sv) * C_ + c0;
        f32x4 a = *(const f32x4*)(s);
        f32x4 b = *(const f32x4*)(s + 4);
        f32x4 c = *(const f32x4*)(s + 8);
        f32x4 d = *(const f32x4*)(s + 12);
        *(f32x4*)&fs[sv][(c0)      ^ m] = a;
        *(f32x4*)&fs[sv][(c0 + 4)  ^ m] = b;
        *(f32x4*)&fs[sv][(c0 + 8)  ^ m] = c;
        *(f32x4*)&fs[sv][(c0 + 12) ^ m] = d;
      }
      __syncthreads();
      { // gather-swizzle, full tile: 2 roles per thread (512 roles total)
        char* tb = (char*)fT2 + ((size_t)p * 128 + ktile) * 8192;
        #pragma unroll
        for (int half = 0; half < 2; ++half) {
          const int r  = half * 256 + tid;
          const int ch = r >> 3;
          const int kq = (r & 7) ^ (ch & 7);
          const int cs = ch ^ (kq << 3);         // swizzled staged column
          const int row0 = kq * 8;
          float f[8];
          #pragma unroll
          for (int e = 0; e < 8; ++e) f[e] = fs[row0 + e][cs];
          u32x4 val = { pack2bf(f[0], f[1]), pack2bf(f[2], f[3]),
                        pack2bf(f[4], f[5]), pack2bf(f[6], f[7]) };
          *(u32x4*)(tb + r * 16) = val;
        }
      }
      __syncthreads();
    }
  } else {
    const int blk2 = blk - 1024;
    const int p = blk2 >> 5, chunk = blk2 & 31;
    const int side = p >> 3, bb = p & 7;
    const float* src = (side ? verts_r : verts_l) + (size_t)bb * (V_ * 3);
    const int v = chunk * 256 + tid;
    const float x = src[v * 3 + 0], y = src[v * 3 + 1], z = src[v * 3 + 2];
    const float n2 = x * x + y * y + z * z;
    constexpr float M2K = -2.0f * KEXP2;
    float* d = vS2 + (size_t)p * 32768 + (size_t)(v >> 6) * 256 + (v & 63);
    d[0] = M2K * x; d[64] = M2K * y; d[128] = M2K * z; d[192] = KEXP2 * n2;
  }
}

// vert register set for one iteration (all static field access -> registers)
struct VRegs {
  f32x4 xa, xb, ya, yb, za, zb, na, nb;
};

// ---------------------------------------------------------------------------
// FUSED interp(both sides) + MLP.
// Round-9 change: verts REMOVED from LDS (they were 8 of 12 ds_read_b128 per
// wave-iter, 16-way broadcasts saturating the per-CU LDS pipe ~120us). Now
// loaded global->reg from L2-resident vS2, prefetched 1 iter ahead into
// alternating named reg sets (vA/vB, manual 2-body unroll, static indexing).
// Feats keep 3-buffer gload_lds + counted vmcnt(10) + raw barrier.
// ---------------------------------------------------------------------------
__global__ __launch_bounds__(512, 4) void fused_kernel(
    const float* __restrict__ locs_l, const float* __restrict__ locs_r,
    const uint16_t* __restrict__ fT2, const float* __restrict__ vS2,
    const float* __restrict__ w1, const float* __restrict__ b1,
    const float* __restrict__ w2, const float* __restrict__ b2,
    float* __restrict__ outp)
{
  __shared__ __align__(16) char  flds[3][16384];      // 3 x (2 subtiles x 8KB)
  __shared__ __align__(16) float xs[32][132];
  __shared__ float densp[32];

  const int bid  = blockIdx.x;
  const int bb   = bid & 7;
  const int tile = bid >> 3;          // 0..63
  const int tid  = threadIdx.x;
  const int wid  = tid >> 6, lane = tid & 63;
  const int g    = wid & 1, h = wid >> 1;      // h in [0,4): 32-vert quarter
  const int ln15 = lane & 15, lg = lane >> 4;
  const int xorv = (ln15 & 7) << 4;
  const f32x4 zero4 = {0.f, 0.f, 0.f, 0.f};

  const int sub  = h >> 1;            // which 8KB subtile
  const int hh   = h & 1;             // 32-vert half within subtile
  const int abfix = sub * 8192 + ln15 * 128 + ((((hh << 2) | lg) << 4) ^ xorv);
  const int voff = hh * 32 + lg * 8;  // lane's vert slice within subtile

  for (int s = 0; s < 2; ++s) {
    const int p = s * 8 + bb;
    const float* locs = (s ? locs_r : locs_l) + (size_t)bb * (L_ * 3);
    const int arow = tile * 32 + g * 16 + ln15;
    const float px = locs[arow * 3 + 0];
    const float py = locs[arow * 3 + 1];
    const float pz = locs[arow * 3 + 2];
    const float pn2p = KEXP2 * (px * px + py * py + pz * pz);
    const f32x4 px4 = {px, px, px, px};
    const f32x4 py4 = {py, py, py, py};
    const f32x4 pz4 = {pz, pz, pz, pz};
    const f32x4 pn4 = {pn2p, pn2p, pn2p, pn2p};

    const char*  ftp = (const char*)fT2 + (size_t)p * (128 * 8192);
    const float* vtp = vS2 + (size_t)p * 32768 + sub * 256 + voff;

    f32x4 acc0 = zero4, acc1 = zero4, acc2 = zero4, acc3 = zero4;
    f32x4 densa = zero4;

    // vert load for tile k into reg set (8 coalesced L2-resident loads)
    auto vload = [&](int k, VRegs& v) {
      const float* b = vtp + k * 512;          // 2 subtiles * 256 floats
      v.xa = *(const f32x4*)(b);       v.xb = *(const f32x4*)(b + 4);
      v.ya = *(const f32x4*)(b + 64);  v.yb = *(const f32x4*)(b + 68);
      v.za = *(const f32x4*)(b + 128); v.zb = *(const f32x4*)(b + 132);
      v.na = *(const f32x4*)(b + 192); v.nb = *(const f32x4*)(b + 196);
    };

    // compute one K-tile from reg verts + LDS feats buffer
    auto body = [&](const VRegs& v, const char* fl) {
      f32x4 d2a = PK_FMA4(v.za, pz4, v.na + pn4);
      d2a = PK_FMA4(v.ya, py4, d2a);
      d2a = PK_FMA4(v.xa, px4, d2a);
      d2a = PK_MAX4(d2a, zero4);
      f32x4 d2b = PK_FMA4(v.zb, pz4, v.nb + pn4);
      d2b = PK_FMA4(v.yb, py4, d2b);
      d2b = PK_FMA4(v.xb, px4, d2b);
      d2b = PK_MAX4(d2b, zero4);
      f32x4 wa, wb;
      #pragma unroll
      for (int e = 0; e < 4; ++e) {
        wa[e] = EXP2(-__builtin_amdgcn_sqrtf(d2a[e]));
        wb[e] = EXP2(-__builtin_amdgcn_sqrtf(d2b[e]));
      }
      densa += wa;
      densa += wb;
      bf16x8 av;
      #pragma unroll
      for (int e = 0; e < 4; ++e) {
        av[e]     = (__bf16)wa[e];
        av[e + 4] = (__bf16)wb[e];
      }
      const s16x8 afrag = __builtin_bit_cast(s16x8, av);
      const s16x8 bf0 = *(const s16x8*)(fl + abfix);
      const s16x8 bf1 = *(const s16x8*)(fl + abfix + 2048);
      const s16x8 bf2 = *(const s16x8*)(fl + abfix + 4096);
      const s16x8 bf3 = *(const s16x8*)(fl + abfix + 6144);
      acc0 = __builtin_amdgcn_mfma_f32_16x16x32_bf16(afrag, bf0, acc0, 0, 0, 0);
      acc1 = __builtin_amdgcn_mfma_f32_16x16x32_bf16(afrag, bf1, acc1, 0, 0, 0);
      acc2 = __builtin_amdgcn_mfma_f32_16x16x32_bf16(afrag, bf2, acc2, 0, 0, 0);
      acc3 = __builtin_amdgcn_mfma_f32_16x16x32_bf16(afrag, bf3, acc3, 0, 0, 0);
    };

    VRegs vA, vB;
    // prologue: verts k=0 -> vA; feats tile 0 -> buf 0
    vload(0, vA);
    gload_lds16(ftp + wid * 2048 + lane * 16,        &flds[0][wid * 2048]);
    gload_lds16(ftp + wid * 2048 + 1024 + lane * 16, &flds[0][wid * 2048 + 1024]);

    const char* gfn = ftp + 16384 + wid * 2048 + lane * 16;
    int cur = 0, nxt = 1;

    // one pipeline step: issue k+1 (verts->vld, feats->flds[nxt]),
    // counted wait, barrier, compute k from vuse + flds[cur]
    #define STEP(K, VUSE, VLD)                                          \
      {                                                                 \
        if ((K) < 63) {                                                 \
          vload((K) + 1, VLD);                                          \
          gload_lds16(gfn,        &flds[nxt][wid * 2048]);              \
          gload_lds16(gfn + 1024, &flds[nxt][wid * 2048 + 1024]);       \
          gfn += 16384;                                                 \
          asm volatile("s_waitcnt vmcnt(10)" ::: "memory");             \
        } else {                                                        \
          asm volatile("s_waitcnt vmcnt(0)" ::: "memory");              \
        }                                                               \
        __builtin_amdgcn_s_barrier();                                   \
        body(VUSE, flds[cur]);                                          \
        cur = (cur == 2) ? 0 : cur + 1;                                 \
        nxt = (nxt == 2) ? 0 : nxt + 1;                                 \
      }

    for (int kt = 0; kt < 64; kt += 2) {
      STEP(kt,     vA, vB);
      STEP(kt + 1, vB, vA);
    }
    #undef STEP

    // lane -> quarter-dens of row (lane&15)
    float dens = (densa.x + densa.y) + (densa.z + densa.w);
    dens += __shfl_xor(dens, 16);
    dens += __shfl_xor(dens, 32);

    // merge 4 k-quarters through xs (phase h==0 writes, 1..3 add)
    #pragma unroll
    for (int ph = 0; ph < 4; ++ph) {
      if (h == ph) {
        if (ph == 0) {
          if (lane < 16) densp[g * 16 + lane] = dens;
          #pragma unroll
          for (int r = 0; r < 4; ++r) {
            const int row = g * 16 + lg * 4 + r;
            xs[row][s * 65 +      ln15] = acc0[r];
            xs[row][s * 65 + 16 + ln15] = acc1[r];
            xs[row][s * 65 + 32 + ln15] = acc2[r];
            xs[row][s * 65 + 48 + ln15] = acc3[r];
          }
        } else {
          if (lane < 16) densp[g * 16 + lane] += dens;
          #pragma unroll
          for (int r = 0; r < 4; ++r) {
            const int row = g * 16 + lg * 4 + r;
            xs[row][s * 65 +      ln15] += acc0[r];
            xs[row][s * 65 + 16 + ln15] += acc1[r];
            xs[row][s * 65 + 32 + ln15] += acc2[r];
            xs[row][s * 65 + 48 + ln15] += acc3[r];
          }
        }
      }
      __syncthreads();
    }
    // normalize by dens; col 64 holds raw dens
    for (int idx = tid; idx < 32 * 64; idx += 512) {
      const int row = idx >> 6, c = idx & 63;
      xs[row][s * 65 + c] *= (1.0f / densp[row]);
    }
    if (tid < 32) xs[tid][s * 65 + 64] = densp[tid];
    __syncthreads();
  }

  // -------------------- in-block MLP (fp32) --------------------
  const int r0 = wid * 4;                     // 4 rows per wave
  float hh0[4] = {0.f,0.f,0.f,0.f}, hh1[4] = {0.f,0.f,0.f,0.f};
  const float* wr0 = w1 + (size_t)lane * F_;
  const float* wr1 = w1 + (size_t)(lane + 64) * F_;

  #pragma unroll 4
  for (int i = 0; i < 128; i += 4) {
    const f32x2 a01 = *(const f32x2*)&wr0[i];
    const f32x2 a23 = *(const f32x2*)&wr0[i + 2];
    const f32x2 c01 = *(const f32x2*)&wr1[i];
    const f32x2 c23 = *(const f32x2*)&wr1[i + 2];
    #pragma unroll
    for (int r = 0; r < 4; ++r) {
      const f32x4 xv = *(const f32x4*)&xs[r0 + r][i];
      hh0[r] = fmaf(xv.x, a01.x, hh0[r]); hh0[r] = fmaf(xv.y, a01.y, hh0[r]);
      hh0[r] = fmaf(xv.z, a23.x, hh0[r]); hh0[r] = fmaf(xv.w, a23.y, hh0[r]);
      hh1[r] = fmaf(xv.x, c01.x, hh1[r]); hh1[r] = fmaf(xv.y, c01.y, hh1[r]);
      hh1[r] = fmaf(xv.z, c23.x, hh1[r]); hh1[r] = fmaf(xv.w, c23.y, hh1[r]);
    }
  }
  { // i-tail: 128,129
    const float a0 = wr0[128], a1 = wr0[129];
    const float c0 = wr1[128], c1 = wr1[129];
    #pragma unroll
    for (int r = 0; r < 4; ++r) {
      const float x0 = xs[r0 + r][128], x1 = xs[r0 + r][129];
      hh0[r] = fmaf(x0, a0, fmaf(x1, a1, hh0[r]));
      hh1[r] = fmaf(x0, c0, fmaf(x1, c1, hh1[r]));
    }
  }
  // j-tail: hidden cols 128,129 via per-row wave reduce
  const float* wr2 = w1 + 128 * F_;
  const float* wr3 = w1 + 129 * F_;
  float hp2[4], hp3[4];
  #pragma unroll
  for (int r = 0; r < 4; ++r) {
    const float xa = xs[r0 + r][lane];
    const float xb = xs[r0 + r][lane + 64];
    float p2 = wr2[lane] * xa + wr2[lane + 64] * xb;
    float p3 = wr3[lane] * xa + wr3[lane + 64] * xb;
    if (lane < 2) {
      const float xc = xs[r0 + r][128 + lane];
      p2 += wr2[128 + lane] * xc;
      p3 += wr3[128 + lane] * xc;
    }
    hp2[r] = wave_sum(p2);
    hp3[r] = wave_sum(p3);
  }
  const float b1a = b1[lane], b1b = b1[lane + 64];
  const float w2a = w2[lane], w2b = w2[lane + 64];
  const float b1c = b1[128], b1d = b1[129];
  const float w2c = w2[128], w2d = w2[129];
  const float b2v = b2[0];
  #pragma unroll
  for (int r = 0; r < 4; ++r) {
    float o = w2a * fmaxf(hh0[r] + b1a, 0.f) + w2b * fmaxf(hh1[r] + b1b, 0.f);
    o = wave_sum(o);
    if (lane == 0) {
      o += w2c * fmaxf(hp2[r] + b1c, 0.f) + w2d * fmaxf(hp3[r] + b1d, 0.f);
      outp[(size_t)bb * L_ + tile * 32 + r0 + r] = o + b2v;
    }
  }
}

// ---------------------------------------------------------------------------
extern "C" void kernel_launch(void* const* d_in, const int* in_sizes, int n_in,
                              void* d_out, int out_size, void* d_ws, size_t ws_size,
                              hipStream_t stream) {
  const float* locs_l  = (const float*)d_in[0];
  const float* locs_r  = (const float*)d_in[1];
  const float* verts_l = (const float*)d_in[2];
  const float* verts_r = (const float*)d_in[3];
  const float* feats_l = (const float*)d_in[4];
  const float* feats_r = (const float*)d_in[5];
  const float* w1 = (const float*)d_in[6];
  const float* b1 = (const float*)d_in[7];
  const float* w2 = (const float*)d_in[8];
  const float* b2 = (const float*)d_in[9];

  char* ws = (char*)d_ws;
  uint16_t* fT2 = (uint16_t*)ws;                 // 16 MiB swizzled feat tiles
  float*    vS2 = (float*)(ws + 16777216);       // 2 MiB pre-scaled vert tiles
  float*    out = (float*)d_out;

  pre_kernel<<<1536, 256, 0, stream>>>(verts_l, verts_r, feats_l, feats_r, fT2, vS2);
  fused_kernel<<<512, 512, 0, stream>>>(locs_l, locs_r, fT2, vS2,
                                        w1, b1, w2, b2, out);
}

// Round 10
// 224.334 us; speedup vs baseline: 1.2905x; 1.2905x over previous
//
#include <hip/hip_runtime.h>
#include <hip/hip_bf16.h>
#include <stdint.h>

#define B_ 8
#define L_ 2048
#define V_ 8192
#define C_ 64
#define F_ 130   // 2*(C+1)

typedef float    f32x4  __attribute__((ext_vector_type(4)));
typedef float    f32x2  __attribute__((ext_vector_type(2)));
typedef short    s16x8  __attribute__((ext_vector_type(8)));
typedef __bf16   bf16x8 __attribute__((ext_vector_type(8)));
typedef uint32_t u32x4  __attribute__((ext_vector_type(4)));

#if __has_builtin(__builtin_amdgcn_exp2f)
#define EXP2(x) __builtin_amdgcn_exp2f(x)
#else
#define EXP2(x) exp2f(x)
#endif

#if __has_builtin(__builtin_elementwise_fma)
#define PK_FMA4(a,b,c) __builtin_elementwise_fma((a),(b),(c))
#else
__device__ __forceinline__ f32x4 PK_FMA4(f32x4 a, f32x4 b, f32x4 c) {
  f32x4 r; for (int i=0;i<4;++i) r[i]=fmaf(a[i],b[i],c[i]); return r;
}
#endif
#if __has_builtin(__builtin_elementwise_max)
#define PK_MAX4(a,b) __builtin_elementwise_max((a),(b))
#else
__device__ __forceinline__ f32x4 PK_MAX4(f32x4 a, f32x4 b) {
  f32x4 r; for (int i=0;i<4;++i) r[i]=fmaxf(a[i],b[i]); return r;
}
#endif

// K = 1/(2.5*ln2); w = exp(-d/2.5) = exp2(-K*d) = exp2(-sqrt(K^2*d2))
constexpr float KEXP2 = (float)(0.57707801635558535 * 0.57707801635558535);

__device__ __forceinline__ uint32_t pack2bf(float a, float b) {
  uint16_t ua = __builtin_bit_cast(uint16_t, (__bf16)a);
  uint16_t ub = __builtin_bit_cast(uint16_t, (__bf16)b);
  return (uint32_t)ua | ((uint32_t)ub << 16);
}

__device__ __forceinline__ float wave_sum(float v) {
  v += __shfl_xor(v, 1);  v += __shfl_xor(v, 2);  v += __shfl_xor(v, 4);
  v += __shfl_xor(v, 8);  v += __shfl_xor(v, 16); v += __shfl_xor(v, 32);
  return v;
}

// async global->LDS, 16B per lane: lds dest = wave-uniform base + lane*16
__device__ __forceinline__ void gload_lds16(const void* g, void* l) {
  __builtin_amdgcn_global_load_lds(
      (const __attribute__((address_space(1))) void*)g,
      (__attribute__((address_space(3))) void*)l, 16, 0, 0);
}

// ---------------------------------------------------------------------------
// PRE: unchanged from rounds 7/8 (passing, full coverage). Do not touch:
// the constant ~72us total-minus-fused gap is harness reset floor, not pre.
// ---------------------------------------------------------------------------
__global__ __launch_bounds__(256) void pre_kernel(
    const float* __restrict__ verts_l, const float* __restrict__ verts_r,
    const float* __restrict__ feats_l, const float* __restrict__ feats_r,
    uint16_t* __restrict__ fT2, float* __restrict__ vS2)
{
  __shared__ float fs[64][68];
  const int blk = blockIdx.x, tid = threadIdx.x;
  if (blk < 1024) {
    const int p = blk >> 6, kt2 = blk & 63;      // 64-vert subtiles 2*kt2, 2*kt2+1
    const int side = p >> 3, bb = p & 7;
    const float* src = (side ? feats_r : feats_l) + (size_t)bb * (V_ * C_);
    #pragma unroll
    for (int sub = 0; sub < 2; ++sub) {
      const int ktile = kt2 * 2 + sub;
      const int v0 = ktile * 64;
      { // stage 64 rows x 64 ch, coalesced; column XOR-swizzle per 8-col block
        const int sv = tid >> 2, c0 = (tid & 3) * 16;
        const int m = ((sv >> 3) & 7) << 3;
        const float* s = src + (size_t)(v0 + sv) * C_ + c0;
        f32x4 a = *(const f32x4*)(s);
        f32x4 b = *(const f32x4*)(s + 4);
        f32x4 c = *(const f32x4*)(s + 8);
        f32x4 d = *(const f32x4*)(s + 12);
        *(f32x4*)&fs[sv][(c0)      ^ m] = a;
        *(f32x4*)&fs[sv][(c0 + 4)  ^ m] = b;
        *(f32x4*)&fs[sv][(c0 + 8)  ^ m] = c;
        *(f32x4*)&fs[sv][(c0 + 12) ^ m] = d;
      }
      __syncthreads();
      { // gather-swizzle, full tile: 2 roles per thread (512 roles total)
        char* tb = (char*)fT2 + ((size_t)p * 128 + ktile) * 8192;
        #pragma unroll
        for (int half = 0; half < 2; ++half) {
          const int r  = half * 256 + tid;
          const int ch = r >> 3;
          const int kq = (r & 7) ^ (ch & 7);
          const int cs = ch ^ (kq << 3);         // swizzled staged column
          const int row0 = kq * 8;
          float f[8];
          #pragma unroll
          for (int e = 0; e < 8; ++e) f[e] = fs[row0 + e][cs];
          u32x4 val = { pack2bf(f[0], f[1]), pack2bf(f[2], f[3]),
                        pack2bf(f[4], f[5]), pack2bf(f[6], f[7]) };
          *(u32x4*)(tb + r * 16) = val;
        }
      }
      __syncthreads();
    }
  } else {
    const int blk2 = blk - 1024;
    const int p = blk2 >> 5, chunk = blk2 & 31;
    const int side = p >> 3, bb = p & 7;
    const float* src = (side ? verts_r : verts_l) + (size_t)bb * (V_ * 3);
    const int v = chunk * 256 + tid;
    const float x = src[v * 3 + 0], y = src[v * 3 + 1], z = src[v * 3 + 2];
    const float n2 = x * x + y * y + z * z;
    constexpr float M2K = -2.0f * KEXP2;
    float* d = vS2 + (size_t)p * 32768 + (size_t)(v >> 6) * 256 + (v & 63);
    d[0] = M2K * x; d[64] = M2K * y; d[128] = M2K * z; d[192] = KEXP2 * n2;
  }
}

// ---------------------------------------------------------------------------
// FUSED interp(both sides) + MLP.
// Round-10: 2 row-tiles per wave (rows 0-15 and 16-31) share vert + B-frag
// LDS reads -> per-pair LDS traffic HALVED (the r9 post-mortem wall).
// Block: 256 thr = 4 waves, wave = vert-quarter h; block = 32 rows x 128
// verts/interval. Grid 512 = 8 b x 64 tiles, 2 blocks/CU. 3-buffer feats
// gload_lds + counted vmcnt(5/4) + raw barrier (r8 discipline).
// ---------------------------------------------------------------------------
__global__ __launch_bounds__(256, 2) void fused_kernel(
    const float* __restrict__ locs_l, const float* __restrict__ locs_r,
    const uint16_t* __restrict__ fT2, const float* __restrict__ vS2,
    const float* __restrict__ w1, const float* __restrict__ b1,
    const float* __restrict__ w2, const float* __restrict__ b2,
    float* __restrict__ outp)
{
  __shared__ __align__(16) char  flds[3][16384];      // 3 x (2 subtiles x 8KB)
  __shared__ __align__(16) float vlds[3][2][4][64];   // [buf][sub][comp][v]
  __shared__ __align__(16) float xs[32][132];
  __shared__ float densp[32];

  const int bid  = blockIdx.x;
  const int bb   = bid & 7;
  const int tile = bid >> 3;          // 0..63
  const int tid  = threadIdx.x;
  const int wid  = tid >> 6, lane = tid & 63;  // wid = vert-quarter h
  const int ln15 = lane & 15, lg = lane >> 4;
  const int xorv = (ln15 & 7) << 4;
  const f32x4 zero4 = {0.f, 0.f, 0.f, 0.f};

  const int sub  = wid >> 1;          // which 8KB subtile
  const int hh   = wid & 1;           // 32-vert half within subtile
  const int abfix = sub * 8192 + ln15 * 128 + ((((hh << 2) | lg) << 4) ^ xorv);
  const int kof  = hh * 32 + lg * 8;  // vert slice within subtile

  for (int s = 0; s < 2; ++s) {
    const int p = s * 8 + bb;
    const float* locs = (s ? locs_r : locs_l) + (size_t)bb * (L_ * 3);
    const int arow0 = tile * 32 + ln15;          // row-tile 0: rows 0-15
    const float qx0 = locs[arow0 * 3 + 0];
    const float qy0 = locs[arow0 * 3 + 1];
    const float qz0 = locs[arow0 * 3 + 2];
    const float qx1 = locs[(arow0 + 16) * 3 + 0];
    const float qy1 = locs[(arow0 + 16) * 3 + 1];
    const float qz1 = locs[(arow0 + 16) * 3 + 2];
    const float qn0 = KEXP2 * (qx0 * qx0 + qy0 * qy0 + qz0 * qz0);
    const float qn1 = KEXP2 * (qx1 * qx1 + qy1 * qy1 + qz1 * qz1);
    const f32x4 px0 = {qx0,qx0,qx0,qx0}, py0 = {qy0,qy0,qy0,qy0};
    const f32x4 pz0 = {qz0,qz0,qz0,qz0}, pn0 = {qn0,qn0,qn0,qn0};
    const f32x4 px1 = {qx1,qx1,qx1,qx1}, py1 = {qy1,qy1,qy1,qy1};
    const f32x4 pz1 = {qz1,qz1,qz1,qz1}, pn1 = {qn1,qn1,qn1,qn1};

    const char*  ftp = (const char*)fT2 + (size_t)p * (128 * 8192);
    const char*  vtp = (const char*)vS2 + (size_t)p * (128 * 1024);

    f32x4 a00 = zero4, a01 = zero4, a02 = zero4, a03 = zero4;  // rows 0-15
    f32x4 a10 = zero4, a11 = zero4, a12 = zero4, a13 = zero4;  // rows 16-31
    f32x4 dac0 = zero4, dac1 = zero4;

    // stage K-tile -> buffer buf (per wave: 1 vert DMA [wid<2] + 4 feat DMA)
    auto stage = [&](int ktile, int buf) {
      const char* gf = ftp + (size_t)ktile * 16384 + wid * 1024 + lane * 16;
      if (wid < 2)
        gload_lds16(vtp + (size_t)ktile * 2048 + wid * 1024 + lane * 16,
                    &vlds[buf][wid][0][0]);
      gload_lds16(gf,         &flds[buf][wid * 1024]);
      gload_lds16(gf + 4096,  &flds[buf][wid * 1024 + 4096]);
      gload_lds16(gf + 8192,  &flds[buf][wid * 1024 + 8192]);
      gload_lds16(gf + 12288, &flds[buf][wid * 1024 + 12288]);
    };

    // w-gen for one row-tile -> bf16 A-frag (verts passed in regs)
    auto wgen = [&](const f32x4& vxa, const f32x4& vxb, const f32x4& vya,
                    const f32x4& vyb, const f32x4& vza, const f32x4& vzb,
                    const f32x4& vna, const f32x4& vnb,
                    const f32x4& px4, const f32x4& py4, const f32x4& pz4,
                    const f32x4& pn4, f32x4& dacc) -> s16x8 {
      f32x4 d2a = PK_FMA4(vza, pz4, vna + pn4);
      d2a = PK_FMA4(vya, py4, d2a);
      d2a = PK_FMA4(vxa, px4, d2a);
      d2a = PK_MAX4(d2a, zero4);
      f32x4 d2b = PK_FMA4(vzb, pz4, vnb + pn4);
      d2b = PK_FMA4(vyb, py4, d2b);
      d2b = PK_FMA4(vxb, px4, d2b);
      d2b = PK_MAX4(d2b, zero4);
      f32x4 wa, wb;
      #pragma unroll
      for (int e = 0; e < 4; ++e) {
        wa[e] = EXP2(-__builtin_amdgcn_sqrtf(d2a[e]));
        wb[e] = EXP2(-__builtin_amdgcn_sqrtf(d2b[e]));
      }
      dacc += wa; dacc += wb;
      bf16x8 av;
      #pragma unroll
      for (int e = 0; e < 4; ++e) { av[e] = (__bf16)wa[e]; av[e+4] = (__bf16)wb[e]; }
      return __builtin_bit_cast(s16x8, av);
    };

    // prologue: tile 0 -> buf 0
    stage(0, 0);

    int cur = 0, nxt = 1;
    for (int kt = 0; kt < 64; ++kt) {
      if (kt < 63) {
        stage(kt + 1, nxt);
        if (wid < 2) { asm volatile("s_waitcnt vmcnt(5)" ::: "memory"); }
        else         { asm volatile("s_waitcnt vmcnt(4)" ::: "memory"); }
      } else {
        asm volatile("s_waitcnt vmcnt(0)" ::: "memory");
      }
      __builtin_amdgcn_s_barrier();   // tile kt fully landed (all waves waited)

      // vert slice (broadcast reads, shared by BOTH row-tiles)
      const f32x4 vxa = *(const f32x4*)&vlds[cur][sub][0][kof];
      const f32x4 vxb = *(const f32x4*)&vlds[cur][sub][0][kof + 4];
      const f32x4 vya = *(const f32x4*)&vlds[cur][sub][1][kof];
      const f32x4 vyb = *(const f32x4*)&vlds[cur][sub][1][kof + 4];
      const f32x4 vza = *(const f32x4*)&vlds[cur][sub][2][kof];
      const f32x4 vzb = *(const f32x4*)&vlds[cur][sub][2][kof + 4];
      const f32x4 vna = *(const f32x4*)&vlds[cur][sub][3][kof];
      const f32x4 vnb = *(const f32x4*)&vlds[cur][sub][3][kof + 4];

      // B-frags (shared by both row-tiles)
      const char* fl = flds[cur];
      const s16x8 bf0 = *(const s16x8*)(fl + abfix);
      const s16x8 bf1 = *(const s16x8*)(fl + abfix + 2048);
      const s16x8 bf2 = *(const s16x8*)(fl + abfix + 4096);
      const s16x8 bf3 = *(const s16x8*)(fl + abfix + 6144);

      const s16x8 af0 = wgen(vxa,vxb,vya,vyb,vza,vzb,vna,vnb,
                             px0,py0,pz0,pn0, dac0);
      a00 = __builtin_amdgcn_mfma_f32_16x16x32_bf16(af0, bf0, a00, 0, 0, 0);
      a01 = __builtin_amdgcn_mfma_f32_16x16x32_bf16(af0, bf1, a01, 0, 0, 0);
      a02 = __builtin_amdgcn_mfma_f32_16x16x32_bf16(af0, bf2, a02, 0, 0, 0);
      a03 = __builtin_amdgcn_mfma_f32_16x16x32_bf16(af0, bf3, a03, 0, 0, 0);

      const s16x8 af1 = wgen(vxa,vxb,vya,vyb,vza,vzb,vna,vnb,
                             px1,py1,pz1,pn1, dac1);
      a10 = __builtin_amdgcn_mfma_f32_16x16x32_bf16(af1, bf0, a10, 0, 0, 0);
      a11 = __builtin_amdgcn_mfma_f32_16x16x32_bf16(af1, bf1, a11, 0, 0, 0);
      a12 = __builtin_amdgcn_mfma_f32_16x16x32_bf16(af1, bf2, a12, 0, 0, 0);
      a13 = __builtin_amdgcn_mfma_f32_16x16x32_bf16(af1, bf3, a13, 0, 0, 0);

      cur = (cur == 2) ? 0 : cur + 1;
      nxt = (nxt == 2) ? 0 : nxt + 1;
    }

    // quarter-dens: lane -> rows (lane&15) and 16+(lane&15)
    float dens0 = (dac0.x + dac0.y) + (dac0.z + dac0.w);
    float dens1 = (dac1.x + dac1.y) + (dac1.z + dac1.w);
    dens0 += __shfl_xor(dens0, 16);  dens0 += __shfl_xor(dens0, 32);
    dens1 += __shfl_xor(dens1, 16);  dens1 += __shfl_xor(dens1, 32);

    // merge 4 vert-quarters through xs (phase wid==0 writes, 1..3 add)
    #pragma unroll
    for (int ph = 0; ph < 4; ++ph) {
      if (wid == ph) {
        if (ph == 0) {
          if (lane < 16) { densp[lane] = dens0; densp[16 + lane] = dens1; }
          #pragma unroll
          for (int r = 0; r < 4; ++r) {
            const int row = lg * 4 + r;
            xs[row][s * 65 +      ln15] = a00[r];
            xs[row][s * 65 + 16 + ln15] = a01[r];
            xs[row][s * 65 + 32 + ln15] = a02[r];
            xs[row][s * 65 + 48 + ln15] = a03[r];
            xs[row + 16][s * 65 +      ln15] = a10[r];
            xs[row + 16][s * 65 + 16 + ln15] = a11[r];
            xs[row + 16][s * 65 + 32 + ln15] = a12[r];
            xs[row + 16][s * 65 + 48 + ln15] = a13[r];
          }
        } else {
          if (lane < 16) { densp[lane] += dens0; densp[16 + lane] += dens1; }
          #pragma unroll
          for (int r = 0; r < 4; ++r) {
            const int row = lg * 4 + r;
            xs[row][s * 65 +      ln15] += a00[r];
            xs[row][s * 65 + 16 + ln15] += a01[r];
            xs[row][s * 65 + 32 + ln15] += a02[r];
            xs[row][s * 65 + 48 + ln15] += a03[r];
            xs[row + 16][s * 65 +      ln15] += a10[r];
            xs[row + 16][s * 65 + 16 + ln15] += a11[r];
            xs[row + 16][s * 65 + 32 + ln15] += a12[r];
            xs[row + 16][s * 65 + 48 + ln15] += a13[r];
          }
        }
      }
      __syncthreads();
    }
    // normalize by dens; col 64 holds raw dens
    for (int idx = tid; idx < 32 * 64; idx += 256) {
      const int row = idx >> 6, c = idx & 63;
      xs[row][s * 65 + c] *= (1.0f / densp[row]);
    }
    if (tid < 32) xs[tid][s * 65 + 64] = densp[tid];
    __syncthreads();
  }

  // -------------------- in-block MLP (fp32), 4 waves x 8 rows --------------
  const int r0 = wid * 8;
  float hh0[8], hh1[8];
  #pragma unroll
  for (int r = 0; r < 8; ++r) { hh0[r] = 0.f; hh1[r] = 0.f; }
  const float* wr0 = w1 + (size_t)lane * F_;
  const float* wr1 = w1 + (size_t)(lane + 64) * F_;

  #pragma unroll 2
  for (int i = 0; i < 128; i += 4) {
    const f32x2 a01 = *(const f32x2*)&wr0[i];
    const f32x2 a23 = *(const f32x2*)&wr0[i + 2];
    const f32x2 c01 = *(const f32x2*)&wr1[i];
    const f32x2 c23 = *(const f32x2*)&wr1[i + 2];
    #pragma unroll
    for (int r = 0; r < 8; ++r) {
      const f32x4 xv = *(const f32x4*)&xs[r0 + r][i];
      hh0[r] = fmaf(xv.x, a01.x, hh0[r]); hh0[r] = fmaf(xv.y, a01.y, hh0[r]);
      hh0[r] = fmaf(xv.z, a23.x, hh0[r]); hh0[r] = fmaf(xv.w, a23.y, hh0[r]);
      hh1[r] = fmaf(xv.x, c01.x, hh1[r]); hh1[r] = fmaf(xv.y, c01.y, hh1[r]);
      hh1[r] = fmaf(xv.z, c23.x, hh1[r]); hh1[r] = fmaf(xv.w, c23.y, hh1[r]);
    }
  }
  { // i-tail: 128,129
    const float a0 = wr0[128], a1 = wr0[129];
    const float c0 = wr1[128], c1 = wr1[129];
    #pragma unroll
    for (int r = 0; r < 8; ++r) {
      const float x0 = xs[r0 + r][128], x1 = xs[r0 + r][129];
      hh0[r] = fmaf(x0, a0, fmaf(x1, a1, hh0[r]));
      hh1[r] = fmaf(x0, c0, fmaf(x1, c1, hh1[r]));
    }
  }
  // j-tail: hidden cols 128,129 via per-row wave reduce
  const float* wr2 = w1 + 128 * F_;
  const float* wr3 = w1 + 129 * F_;
  float hp2[8], hp3[8];
  #pragma unroll
  for (int r = 0; r < 8; ++r) {
    const float xa = xs[r0 + r][lane];
    const float xb = xs[r0 + r][lane + 64];
    float p2 = wr2[lane] * xa + wr2[lane + 64] * xb;
    float p3 = wr3[lane] * xa + wr3[lane + 64] * xb;
    if (lane < 2) {
      const float xc = xs[r0 + r][128 + lane];
      p2 += wr2[128 + lane] * xc;
      p3 += wr3[128 + lane] * xc;
    }
    hp2[r] = wave_sum(p2);
    hp3[r] = wave_sum(p3);
  }
  const float b1a = b1[lane], b1b = b1[lane + 64];
  const float w2a = w2[lane], w2b = w2[lane + 64];
  const float b1c = b1[128], b1d = b1[129];
  const float w2c = w2[128], w2d = w2[129];
  const float b2v = b2[0];
  #pragma unroll
  for (int r = 0; r < 8; ++r) {
    float o = w2a * fmaxf(hh0[r] + b1a, 0.f) + w2b * fmaxf(hh1[r] + b1b, 0.f);
    o = wave_sum(o);
    if (lane == 0) {
      o += w2c * fmaxf(hp2[r] + b1c, 0.f) + w2d * fmaxf(hp3[r] + b1d, 0.f);
      outp[(size_t)bb * L_ + tile * 32 + r0 + r] = o + b2v;
    }
  }
}

// ---------------------------------------------------------------------------
extern "C" void kernel_launch(void* const* d_in, const int* in_sizes, int n_in,
                              void* d_out, int out_size, void* d_ws, size_t ws_size,
                              hipStream_t stream) {
  const float* locs_l  = (const float*)d_in[0];
  const float* locs_r  = (const float*)d_in[1];
  const float* verts_l = (const float*)d_in[2];
  const float* verts_r = (const float*)d_in[3];
  const float* feats_l = (const float*)d_in[4];
  const float* feats_r = (const float*)d_in[5];
  const float* w1 = (const float*)d_in[6];
  const float* b1 = (const float*)d_in[7];
  const float* w2 = (const float*)d_in[8];
  const float* b2 = (const float*)d_in[9];

  char* ws = (char*)d_ws;
  uint16_t* fT2 = (uint16_t*)ws;                 // 16 MiB swizzled feat tiles
  float*    vS2 = (float*)(ws + 16777216);       // 2 MiB pre-scaled vert tiles
  float*    out = (float*)d_out;

  pre_kernel<<<1536, 256, 0, stream>>>(verts_l, verts_r, feats_l, feats_r, fT2, vS2);
  fused_kernel<<<512, 256, 0, stream>>>(locs_l, locs_r, fT2, vS2,
                                        w1, b1, w2, b2, out);
}